// Round 5
// baseline (238.665 us; speedup 1.0000x reference)
//
#include <hip/hip_runtime.h>
#include <hip/hip_bf16.h>
#include <stdint.h>

// ============================================================================
// Fused 2-layer tanh RNN (batch_first, eval) + linear head, MI355X gfx950.
//
// Round 5 change (baseline 78.0 us, latency-bound: MfmaUtil 15.8%, VALUBusy
// 29.5%, Occupancy 10.4% = 1 wave/SIMD):
//   * 2 independent chains per CU: 512 blocks x 8 batch rows (was 256 x 16).
//     M=16 MFMA tiles are half-phantom (rows 8-15 follow a harmless x=0
//     trajectory; never stored to global). __launch_bounds__(256,2) + 72 KB
//     LDS/CU => 2 blocks/CU; each SIMD hosts 2 waves from INDEPENDENT blocks,
//     so one chain's ds_read/MFMA-dep/barrier stalls are absorbed by the
//     other (m114: pipes overlap across waves). ~65% of each step is
//     currently stall with nothing to hide it.
//   * x staging now only 8 rows => stager waves 0-1 only (wave-uniform).
//   * X buffers fully zeroed once at init (phantom rows stay zero).
// Unchanged from round 4: lgkmcnt-only barriers (vmcnt stays in flight),
// 5-op tanh, RNE hi/lo splits, chains <= 4, h1@Whh1 hoisted into phase A,
// 2 barriers/step, per-wave 16-col tiles, mfma_f32_16x16x32_bf16.
//
// Fragment layouts (A/B: m92-ladder-consistent; D: m89-verified):
//   A (16Mx32K): row = lane&15, k = 8*(lane>>4) + j
//   B (32Kx16N): col = lane&15, k = 8*(lane>>4) + j
//   D (16x16)  : col = lane&15, row = 4*(lane>>4) + reg
// ============================================================================

typedef float  f32x4 __attribute__((ext_vector_type(4)));
typedef short  s16x8 __attribute__((ext_vector_type(8)));
typedef unsigned int u32;

#define TSTEPS 64
#define FIN    124
#define HID    64
#define ROWS   8   // valid batch rows per block (rows 8-15 phantom)

__device__ __forceinline__ f32x4 zero4() {
  f32x4 z = {0.f, 0.f, 0.f, 0.f};
  return z;
}

// Barrier with LDS-only drain: does NOT wait vmcnt, so global prefetch loads
// stay in flight across it (T4 pattern; __syncthreads would drain vmcnt(0)).
__device__ __forceinline__ void barrier_lds() {
  asm volatile("s_waitcnt lgkmcnt(0)" ::: "memory");
  __builtin_amdgcn_s_barrier();
  asm volatile("" ::: "memory");
}

// RNE split of 8 consecutive fp32 into hi/lo bf16x8 (v = hi + lo + O(2^-18)).
__device__ __forceinline__ void split8(const f32x4 a, const f32x4 b,
                                       s16x8& hi, s16x8& lo) {
  float e[8] = {a[0], a[1], a[2], a[3], b[0], b[1], b[2], b[3]};
  s16x8 h, l;
#pragma unroll
  for (int p = 0; p < 8; ++p) {
    float v = e[p];
    __hip_bfloat16 bh = __float2bfloat16(v);           // RNE
    float r = v - __bfloat162float(bh);
    __hip_bfloat16 bl = __float2bfloat16(r);
    h[p] = (short)__builtin_bit_cast(unsigned short, bh);
    l[p] = (short)__builtin_bit_cast(unsigned short, bl);
  }
  hi = h;
  lo = l;
}

__device__ __forceinline__ f32x4 MFMA(s16x8 a, s16x8 b, f32x4 c) {
  return __builtin_amdgcn_mfma_f32_16x16x32_bf16(a, b, c, 0, 0, 0);
}

// tanh(x) = 1 - 2/(e^{2x}+1); e^{2x} = exp2(x * 2/ln2). Inf-safe unclamped.
__device__ __forceinline__ float tanh_f(float x) {
  float e = __builtin_amdgcn_exp2f(x * 2.885390081777927f);
  return __builtin_fmaf(-2.f, __builtin_amdgcn_rcpf(e + 1.f), 1.f);
}

__global__ __launch_bounds__(256, 2) void rnn2_fused_kernel(
    const float* __restrict__ x,
    const float* __restrict__ Wih0, const float* __restrict__ Whh0,
    const float* __restrict__ bih0, const float* __restrict__ bhh0,
    const float* __restrict__ Wih1, const float* __restrict__ Whh1,
    const float* __restrict__ bih1, const float* __restrict__ bhh1,
    const float* __restrict__ Wfc,  const float* __restrict__ bfc,
    float* __restrict__ out) {
  __shared__ __align__(16) unsigned short XH[2][16][136];
  __shared__ __align__(16) unsigned short XL[2][16][136];
  __shared__ __align__(16) unsigned short S0H[2][16][72];
  __shared__ __align__(16) unsigned short S0L[2][16][72];
  __shared__ __align__(16) unsigned short S1H[2][16][72];
  __shared__ __align__(16) unsigned short S1L[2][16][72];
  __shared__ float WFC[64];
  __shared__ float RED[64];

  const int tid  = (int)threadIdx.x;
  const int lane = tid & 63;
  const int wv   = tid >> 6;
  const int r16  = lane & 15;
  const int g    = lane >> 4;
  const int col  = 16 * wv + r16;
  const int n0   = (int)blockIdx.x * ROWS;

  // ---- weight fragments (pre-split, register-resident) ----
  s16x8 WH[3][2][2];  // [0=Whh0 1=Wih1 2=Whh1][K-chunk][0=hi 1=lo]
  {
    const float* Wp[3] = {Whh0, Wih1, Whh1};
#pragma unroll
    for (int p = 0; p < 3; ++p) {
#pragma unroll
      for (int c = 0; c < 2; ++c) {
        const float* base = Wp[p] + col * HID + 32 * c + 8 * g;
        f32x4 a = *(const f32x4*)base;
        f32x4 b = *(const f32x4*)(base + 4);
        split8(a, b, WH[p][c][0], WH[p][c][1]);
      }
    }
  }
  s16x8 WI[4][2];  // W_ih0, K padded 124 -> 128
#pragma unroll
  for (int c = 0; c < 4; ++c) {
    const float* base = Wih0 + col * FIN + 32 * c + 8 * g;
    f32x4 a = *(const f32x4*)base;
    f32x4 b = zero4();
    if (!(c == 3 && g == 3)) b = *(const f32x4*)(base + 4);
    split8(a, b, WI[c][0], WI[c][1]);
  }

  const float bias0 = bih0[col] + bhh0[col];
  const float bias1 = bih1[col] + bhh1[col];

  // ---- zero initial state buffers AND x buffers (phantom rows 8-15 of X
  //      must stay zero forever; stagers only ever write rows 0-7). ----
  {
    u32* z0 = (u32*)&S0H[0][0][0];
    u32* z1 = (u32*)&S0L[0][0][0];
    u32* z2 = (u32*)&S1H[0][0][0];
    u32* z3 = (u32*)&S1L[0][0][0];
    for (int i = tid; i < 16 * 72 / 2; i += 256) {
      z0[i] = 0; z1[i] = 0; z2[i] = 0; z3[i] = 0;
    }
    u32* zx0 = (u32*)&XH[0][0][0];
    u32* zx1 = (u32*)&XL[0][0][0];
    for (int i = tid; i < 2 * 16 * 136 / 2; i += 256) {
      zx0[i] = 0; zx1[i] = 0;
    }
  }
  if (tid < 64) WFC[tid] = Wfc[tid];
  barrier_lds();  // zeroing visible before t=0 staging overwrites rows 0-7

  // ---- x staging: waves 0-1 (tid<128) own rows 0-7, 8 floats each ----
  const bool stager = (tid < 128);
  const int xr = tid >> 4;  // 0..7 for stagers
  const int xs = tid & 15;  // k-octet (xs==15 covers k=120..127, pad)
  const float* xrow = x + (size_t)(n0 + (stager ? xr : 0)) * (TSTEPS * FIN);
  f32x4 xa, xb;
  if (stager) {  // t = 0: load + stage into buffer 0
    const float* b0 = xrow + 8 * xs;
    xa = *(const f32x4*)b0;
    xb = zero4();
    if (xs != 15) xb = *(const f32x4*)(b0 + 4);
    s16x8 fh, fl;
    split8(xa, xb, fh, fl);
    *(s16x8*)&XH[0][xr][8 * xs] = fh;
    *(s16x8*)&XL[0][xr][8 * xs] = fl;
    // t = 1 into regs
    const float* b1 = xrow + FIN + 8 * xs;
    xa = *(const f32x4*)b1;
    xb = zero4();
    if (xs != 15) xb = *(const f32x4*)(b1 + 4);
  }
  barrier_lds();

  // ---- time loop: 2 LDS-only barriers / step ----
#pragma unroll 2
  for (int t = 0; t < TSTEPS; ++t) {
    const int P = t & 1;

    // 1) stage x_{t+1}; 2) issue x_{t+2} loads (fly across barriers).
    if (stager) {
      s16x8 fh, fl;
      split8(xa, xb, fh, fl);
      *(s16x8*)&XH[1 - P][xr][8 * xs] = fh;
      *(s16x8*)&XL[1 - P][xr][8 * xs] = fl;
      int t2 = (t + 2 < TSTEPS) ? (t + 2) : (TSTEPS - 1);
      const float* bp = xrow + t2 * FIN + 8 * xs;
      xa = *(const f32x4*)bp;
      xb = zero4();
      if (xs != 15) xb = *(const f32x4*)(bp + 4);
    }

    // 3) Load all pre-barrier A-fragments (h0 prev, x cur, h1 prev).
    s16x8 h0h[2], h0l[2], xh[4], xl[4], h1h[2], h1l[2];
#pragma unroll
    for (int c = 0; c < 2; ++c) {
      h0h[c] = *(const s16x8*)&S0H[P][r16][32 * c + 8 * g];
      h0l[c] = *(const s16x8*)&S0L[P][r16][32 * c + 8 * g];
      h1h[c] = *(const s16x8*)&S1H[P][r16][32 * c + 8 * g];
      h1l[c] = *(const s16x8*)&S1L[P][r16][32 * c + 8 * g];
    }
#pragma unroll
    for (int c = 0; c < 4; ++c) {
      xh[c] = *(const s16x8*)&XH[P][r16][32 * c + 8 * g];
      xl[c] = *(const s16x8*)&XL[P][r16][32 * c + 8 * g];
    }

    // 4) Phase A MFMAs + hoisted h1_prev@Whh1^T. Chains <= 4, round-robin.
    f32x4 a0 = {bias0, bias0, bias0, bias0};
    f32x4 a1 = zero4();
    f32x4 a2 = zero4();
    f32x4 a3 = zero4();
    f32x4 a4 = zero4();
    f32x4 a5 = zero4();
    f32x4 b0 = {bias1, bias1, bias1, bias1};
    f32x4 b1 = zero4();

    a0 = MFMA(h0h[0], WH[0][0][0], a0);
    a1 = MFMA(h0h[0], WH[0][0][1], a1);
    a2 = MFMA(h0l[0], WH[0][0][0], a2);
    a3 = MFMA(xh[2], WI[2][0], a3);
    a4 = MFMA(xh[2], WI[2][1], a4);
    a5 = MFMA(xl[2], WI[2][0], a5);
    b0 = MFMA(h1h[0], WH[2][0][0], b0);
    b1 = MFMA(h1l[0], WH[2][0][0], b1);

    a0 = MFMA(h0h[1], WH[0][1][0], a0);
    a1 = MFMA(h0h[1], WH[0][1][1], a1);
    a2 = MFMA(h0l[1], WH[0][1][0], a2);
    a3 = MFMA(xh[3], WI[3][0], a3);
    a4 = MFMA(xh[3], WI[3][1], a4);
    a5 = MFMA(xl[3], WI[3][0], a5);
    b0 = MFMA(h1h[1], WH[2][1][0], b0);
    b1 = MFMA(h1l[1], WH[2][1][0], b1);

    a0 = MFMA(xh[0], WI[0][0], a0);
    a1 = MFMA(xh[0], WI[0][1], a1);
    a2 = MFMA(xl[0], WI[0][0], a2);
    b0 = MFMA(h1h[0], WH[2][0][1], b0);

    a0 = MFMA(xh[1], WI[1][0], a0);
    a1 = MFMA(xh[1], WI[1][1], a1);
    a2 = MFMA(xl[1], WI[1][0], a2);
    b0 = MFMA(h1h[1], WH[2][1][1], b0);

    // 5) h0_new = tanh(sum) -> S0[1-P] as RNE hi/lo (D: row=4g+i, col=col).
#pragma unroll
    for (int i = 0; i < 4; ++i) {
      float h = tanh_f(((a0[i] + a1[i]) + (a2[i] + a3[i])) + (a4[i] + a5[i]));
      __hip_bfloat16 bh = __float2bfloat16(h);
      float rl = h - __bfloat162float(bh);
      __hip_bfloat16 bl = __float2bfloat16(rl);
      S0H[1 - P][4 * g + i][col] = __builtin_bit_cast(unsigned short, bh);
      S0L[1 - P][4 * g + i][col] = __builtin_bit_cast(unsigned short, bl);
    }
    barrier_lds();

    // 6) Phase B tail: h0_new @ Wih1^T (6 MFMAs, chains <= 4).
    f32x4 b2 = zero4();
    f32x4 b3 = zero4();
#pragma unroll
    for (int c = 0; c < 2; ++c) {
      s16x8 ah = *(const s16x8*)&S0H[1 - P][r16][32 * c + 8 * g];
      s16x8 al = *(const s16x8*)&S0L[1 - P][r16][32 * c + 8 * g];
      b2 = MFMA(ah, WH[1][c][0], b2);
      b3 = MFMA(al, WH[1][c][0], b3);
      b2 = MFMA(ah, WH[1][c][1], b2);
    }
#pragma unroll
    for (int i = 0; i < 4; ++i) {
      float h = tanh_f((b0[i] + b1[i]) + (b2[i] + b3[i]));
      __hip_bfloat16 bh = __float2bfloat16(h);
      float rl = h - __bfloat162float(bh);
      __hip_bfloat16 bl = __float2bfloat16(rl);
      S1H[1 - P][4 * g + i][col] = __builtin_bit_cast(unsigned short, bh);
      S1L[1 - P][4 * g + i][col] = __builtin_bit_cast(unsigned short, bl);
    }
    barrier_lds();
  }

  // ---- FC head: out[n] = h1[n] . Wfc + bfc, rows 0-7 only.
  // Final h1 in buffer 0 (t=63: P=1, wrote 1-P=0). ----
  if (tid < 64) {
    const int r = tid & 7;        // row 0..7
    const int q = tid >> 3;       // col-chunk 0..7 (8 cols each)
    float acc = 0.f;
#pragma unroll
    for (int k = 0; k < 8; ++k) {
      int kk = 8 * q + k;
      float hv = __uint_as_float(((u32)S1H[0][r][kk]) << 16) +
                 __uint_as_float(((u32)S1L[0][r][kk]) << 16);
      acc += hv * WFC[kk];
    }
    RED[tid] = acc;
  }
  barrier_lds();
  if (tid < ROWS) {
    float o = bfc[0];
#pragma unroll
    for (int j = 0; j < 8; ++j) o += RED[tid + 8 * j];
    out[n0 + tid] = o;
  }
}

extern "C" void kernel_launch(void* const* d_in, const int* in_sizes, int n_in,
                              void* d_out, int out_size, void* d_ws,
                              size_t ws_size, hipStream_t stream) {
  (void)in_sizes; (void)n_in; (void)d_ws; (void)ws_size; (void)out_size;
  const float* x    = (const float*)d_in[0];
  const float* Wih0 = (const float*)d_in[1];
  const float* Whh0 = (const float*)d_in[2];
  const float* bih0 = (const float*)d_in[3];
  const float* bhh0 = (const float*)d_in[4];
  const float* Wih1 = (const float*)d_in[5];
  const float* Whh1 = (const float*)d_in[6];
  const float* bih1 = (const float*)d_in[7];
  const float* bhh1 = (const float*)d_in[8];
  const float* Wfc  = (const float*)d_in[9];
  const float* bfc  = (const float*)d_in[10];

  rnn2_fused_kernel<<<512, 256, 0, stream>>>(
      x, Wih0, Whh0, bih0, bhh0, Wih1, Whh1, bih1, bhh1, Wfc, bfc,
      (float*)d_out);
}

// Round 6
// 220.201 us; speedup vs baseline: 1.0839x; 1.0839x over previous
//
#include <hip/hip_runtime.h>
#include <hip/hip_bf16.h>
#include <stdint.h>

// ============================================================================
// Fused 2-layer tanh RNN (batch_first, eval) + linear head, MI355X gfx950.
//
// Round 6: wave-specialized producer/consumer pipeline.
//   Baselines: r4 = 78.0 us (1 wave/SIMD, 2 barriers/step, latency-bound),
//   r5 = 98.1 us (FAILED: phantom rows doubled work for 2 waves/SIMD; but
//   per-work throughput rose 1.59x => overlap works, feed it useful work).
//   This round: 256 blocks x 512 threads (8 waves), 16 REAL rows/block.
//     waves 0-3 (L0): h0 recurrence  (18 MFMAs/step, 6 chains of 3)
//     waves 4-7 (L1): h1 recurrence  (12 MFMAs/step, 4 chains of 3)
//                     + x staging/prefetch, one step SKEWED behind L0.
//   => 2 waves/SIMD of independent work, ONE lgkm-only barrier per step
//   (65 steps incl. skew tail), no duplicated FLOPs.
//
// Parity (s = block-step): L0 reads S0[s&1] (=h0(s-1)), writes S0[1-(s&1)].
// L1 (s>=1) reads h0(s-1)=S0[s&1] and h1(s-2)=S1[1-(s&1)], writes S1[s&1].
// Final h1(63) -> S1[0] at s=64. X: stage x(s+1) into X[(s+1)&1] at s.
//
// Kept from r4: lgkmcnt-only barriers (global prefetch flies across),
// 5-op tanh, RNE hi/lo bf16 splits (3-term products), chains <= 4.
//
// Fragment layouts (A/B: m92-ladder-consistent; D: m89-verified):
//   A (16Mx32K): row = lane&15, k = 8*(lane>>4) + j
//   B (32Kx16N): col = lane&15, k = 8*(lane>>4) + j
//   D (16x16)  : col = lane&15, row = 4*(lane>>4) + reg
// ============================================================================

typedef float  f32x4 __attribute__((ext_vector_type(4)));
typedef short  s16x8 __attribute__((ext_vector_type(8)));
typedef unsigned int u32;

#define TSTEPS 64
#define FIN    124
#define HID    64

__device__ __forceinline__ f32x4 zero4() {
  f32x4 z = {0.f, 0.f, 0.f, 0.f};
  return z;
}

// Barrier with LDS-only drain (T4): global prefetch loads stay in flight.
__device__ __forceinline__ void barrier_lds() {
  asm volatile("s_waitcnt lgkmcnt(0)" ::: "memory");
  __builtin_amdgcn_s_barrier();
  asm volatile("" ::: "memory");
}

// RNE split of 8 consecutive fp32 into hi/lo bf16x8 (v = hi + lo + O(2^-18)).
__device__ __forceinline__ void split8(const f32x4 a, const f32x4 b,
                                       s16x8& hi, s16x8& lo) {
  float e[8] = {a[0], a[1], a[2], a[3], b[0], b[1], b[2], b[3]};
  s16x8 h, l;
#pragma unroll
  for (int p = 0; p < 8; ++p) {
    float v = e[p];
    __hip_bfloat16 bh = __float2bfloat16(v);           // RNE
    float r = v - __bfloat162float(bh);
    __hip_bfloat16 bl = __float2bfloat16(r);
    h[p] = (short)__builtin_bit_cast(unsigned short, bh);
    l[p] = (short)__builtin_bit_cast(unsigned short, bl);
  }
  hi = h;
  lo = l;
}

__device__ __forceinline__ f32x4 MFMA(s16x8 a, s16x8 b, f32x4 c) {
  return __builtin_amdgcn_mfma_f32_16x16x32_bf16(a, b, c, 0, 0, 0);
}

// tanh(x) = 1 - 2/(e^{2x}+1); e^{2x} = exp2(x * 2/ln2). Inf-safe unclamped.
__device__ __forceinline__ float tanh_f(float x) {
  float e = __builtin_amdgcn_exp2f(x * 2.885390081777927f);
  return __builtin_fmaf(-2.f, __builtin_amdgcn_rcpf(e + 1.f), 1.f);
}

__global__ __launch_bounds__(512, 2) void rnn2_fused_kernel(
    const float* __restrict__ x,
    const float* __restrict__ Wih0, const float* __restrict__ Whh0,
    const float* __restrict__ bih0, const float* __restrict__ bhh0,
    const float* __restrict__ Wih1, const float* __restrict__ Whh1,
    const float* __restrict__ bih1, const float* __restrict__ bhh1,
    const float* __restrict__ Wfc,  const float* __restrict__ bfc,
    float* __restrict__ out) {
  __shared__ __align__(16) unsigned short XH[2][16][136];
  __shared__ __align__(16) unsigned short XL[2][16][136];
  __shared__ __align__(16) unsigned short S0H[2][16][72];
  __shared__ __align__(16) unsigned short S0L[2][16][72];
  __shared__ __align__(16) unsigned short S1H[2][16][72];
  __shared__ __align__(16) unsigned short S1L[2][16][72];
  __shared__ float WFC[64];
  __shared__ float RED[64];

  const int tid  = (int)threadIdx.x;
  const int lane = tid & 63;
  const int wv   = tid >> 6;        // 0..7; L0 = wv<4, L1 = wv>=4
  const bool L0  = (wv < 4);
  const int r16  = lane & 15;
  const int g    = lane >> 4;
  const int col  = 16 * (wv & 3) + r16;
  const int n0   = (int)blockIdx.x * 16;

  // ---- weight fragments (pre-split, register-resident, per role) ----
  // L0: WA = Wih0 (4 K-chunks, tail-masked), WB = Whh0 (2 chunks).
  // L1: WA[0..1] = Wih1, WA[2..3] = Whh1; WB unused.
  s16x8 WA[4][2];
  s16x8 WB[2][2];
  float bias;
  if (L0) {
#pragma unroll
    for (int c = 0; c < 4; ++c) {
      const float* base = Wih0 + col * FIN + 32 * c + 8 * g;
      f32x4 a = *(const f32x4*)base;
      f32x4 b = zero4();
      if (!(c == 3 && g == 3)) b = *(const f32x4*)(base + 4);  // k>=124 pad
      split8(a, b, WA[c][0], WA[c][1]);
    }
#pragma unroll
    for (int c = 0; c < 2; ++c) {
      const float* base = Whh0 + col * HID + 32 * c + 8 * g;
      split8(*(const f32x4*)base, *(const f32x4*)(base + 4),
             WB[c][0], WB[c][1]);
    }
    bias = bih0[col] + bhh0[col];
  } else {
#pragma unroll
    for (int c = 0; c < 2; ++c) {
      const float* base = Wih1 + col * HID + 32 * c + 8 * g;
      split8(*(const f32x4*)base, *(const f32x4*)(base + 4),
             WA[c][0], WA[c][1]);
      const float* base2 = Whh1 + col * HID + 32 * c + 8 * g;
      split8(*(const f32x4*)base2, *(const f32x4*)(base2 + 4),
             WA[2 + c][0], WA[2 + c][1]);
    }
    bias = bih1[col] + bhh1[col];
  }

  // ---- zero parity-0 state buffers; stage FC weights ----
  {
    u32* z0 = (u32*)&S0H[0][0][0];
    u32* z1 = (u32*)&S0L[0][0][0];
    u32* z2 = (u32*)&S1H[0][0][0];
    u32* z3 = (u32*)&S1L[0][0][0];
    for (int i = tid; i < 16 * 72 / 2; i += 512) {
      z0[i] = 0; z1[i] = 0; z2[i] = 0; z3[i] = 0;
    }
  }
  if (tid < 64) WFC[tid] = Wfc[tid];

  // ---- x staging bootstrap (L1 threads: idx -> row, k-octet) ----
  const int sidx = tid - 256;          // 0..255 for L1
  const int xr = sidx >> 4;            // row 0..15
  const int xs = sidx & 15;            // k-octet (xs==15: k=120..127 pad)
  const float* xrow = x + (size_t)(n0 + (L0 ? 0 : xr)) * (TSTEPS * FIN);
  f32x4 xa, xb;
  if (!L0) {
    const float* b0 = xrow + 8 * xs;   // x(0) -> X[0]
    xa = *(const f32x4*)b0;
    xb = zero4();
    if (xs != 15) xb = *(const f32x4*)(b0 + 4);
    s16x8 fh, fl;
    split8(xa, xb, fh, fl);
    *(s16x8*)&XH[0][xr][8 * xs] = fh;
    *(s16x8*)&XL[0][xr][8 * xs] = fl;
    const float* b1 = xrow + FIN + 8 * xs;  // x(1) -> regs
    xa = *(const f32x4*)b1;
    xb = zero4();
    if (xs != 15) xb = *(const f32x4*)(b1 + 4);
  }
  barrier_lds();

  // ---- pipeline: 65 block-steps, ONE barrier each ----
#pragma unroll 2
  for (int s = 0; s <= TSTEPS; ++s) {
    const int P = s & 1;

    if (L0) {
      if (s < TSTEPS) {
        // h0(s) = tanh(x(s)@Wih0^T + h0(s-1)@Whh0^T + bias0)
        s16x8 hh[2], hl[2], xh[4], xl[4];
#pragma unroll
        for (int c = 0; c < 2; ++c) {
          hh[c] = *(const s16x8*)&S0H[P][r16][32 * c + 8 * g];
          hl[c] = *(const s16x8*)&S0L[P][r16][32 * c + 8 * g];
        }
#pragma unroll
        for (int c = 0; c < 4; ++c) {
          xh[c] = *(const s16x8*)&XH[P][r16][32 * c + 8 * g];
          xl[c] = *(const s16x8*)&XL[P][r16][32 * c + 8 * g];
        }
        f32x4 a0 = {bias, bias, bias, bias};
        f32x4 a1 = zero4(), a2 = zero4(), a3 = zero4(),
              a4 = zero4(), a5 = zero4();
        // round 1
        a0 = MFMA(hh[0], WB[0][0], a0);
        a1 = MFMA(hh[0], WB[0][1], a1);
        a2 = MFMA(hl[0], WB[0][0], a2);
        a3 = MFMA(xh[1], WA[1][0], a3);
        a4 = MFMA(xh[1], WA[1][1], a4);
        a5 = MFMA(xl[1], WA[1][0], a5);
        // round 2
        a0 = MFMA(hh[1], WB[1][0], a0);
        a1 = MFMA(hh[1], WB[1][1], a1);
        a2 = MFMA(hl[1], WB[1][0], a2);
        a3 = MFMA(xh[2], WA[2][0], a3);
        a4 = MFMA(xh[2], WA[2][1], a4);
        a5 = MFMA(xl[2], WA[2][0], a5);
        // round 3
        a0 = MFMA(xh[0], WA[0][0], a0);
        a1 = MFMA(xh[0], WA[0][1], a1);
        a2 = MFMA(xl[0], WA[0][0], a2);
        a3 = MFMA(xh[3], WA[3][0], a3);
        a4 = MFMA(xh[3], WA[3][1], a4);
        a5 = MFMA(xl[3], WA[3][0], a5);
#pragma unroll
        for (int i = 0; i < 4; ++i) {
          float h = tanh_f(((a0[i] + a1[i]) + (a2[i] + a3[i])) +
                           (a4[i] + a5[i]));
          __hip_bfloat16 bh = __float2bfloat16(h);
          float rl = h - __bfloat162float(bh);
          __hip_bfloat16 bl = __float2bfloat16(rl);
          S0H[1 - P][4 * g + i][col] = __builtin_bit_cast(unsigned short, bh);
          S0L[1 - P][4 * g + i][col] = __builtin_bit_cast(unsigned short, bl);
        }
      }
    } else {
      // stage x(s+1) -> X[1-P]; prefetch x(s+2). Issue FIRST (loads fly).
      if (s < TSTEPS - 1) {
        s16x8 fh, fl;
        split8(xa, xb, fh, fl);
        *(s16x8*)&XH[1 - P][xr][8 * xs] = fh;
        *(s16x8*)&XL[1 - P][xr][8 * xs] = fl;
        int t2 = (s + 2 < TSTEPS) ? (s + 2) : (TSTEPS - 1);
        const float* bp = xrow + t2 * FIN + 8 * xs;
        xa = *(const f32x4*)bp;
        xb = zero4();
        if (xs != 15) xb = *(const f32x4*)(bp + 4);
      }
      if (s >= 1) {
        // h1(s-1) = tanh(h0(s-1)@Wih1^T + h1(s-2)@Whh1^T + bias1)
        s16x8 gh[2], gl[2], qh[2], ql[2];
#pragma unroll
        for (int c = 0; c < 2; ++c) {
          gh[c] = *(const s16x8*)&S0H[P][r16][32 * c + 8 * g];      // h0(s-1)
          gl[c] = *(const s16x8*)&S0L[P][r16][32 * c + 8 * g];
          qh[c] = *(const s16x8*)&S1H[1 - P][r16][32 * c + 8 * g];  // h1(s-2)
          ql[c] = *(const s16x8*)&S1L[1 - P][r16][32 * c + 8 * g];
        }
        f32x4 b0 = {bias, bias, bias, bias};
        f32x4 b1 = zero4(), b2 = zero4(), b3 = zero4();
        // round 1
        b0 = MFMA(gh[0], WA[0][0], b0);
        b1 = MFMA(gh[0], WA[0][1], b1);
        b2 = MFMA(gl[0], WA[0][0], b2);
        b3 = MFMA(ql[0], WA[2][0], b3);
        // round 2
        b0 = MFMA(gh[1], WA[1][0], b0);
        b1 = MFMA(gh[1], WA[1][1], b1);
        b2 = MFMA(gl[1], WA[1][0], b2);
        b3 = MFMA(ql[1], WA[3][0], b3);
        // round 3
        b0 = MFMA(qh[0], WA[2][0], b0);
        b1 = MFMA(qh[1], WA[3][0], b1);
        b2 = MFMA(qh[0], WA[2][1], b2);
        b3 = MFMA(qh[1], WA[3][1], b3);
#pragma unroll
        for (int i = 0; i < 4; ++i) {
          float h = tanh_f((b0[i] + b1[i]) + (b2[i] + b3[i]));
          __hip_bfloat16 bh = __float2bfloat16(h);
          float rl = h - __bfloat162float(bh);
          __hip_bfloat16 bl = __float2bfloat16(rl);
          S1H[P][4 * g + i][col] = __builtin_bit_cast(unsigned short, bh);
          S1L[P][4 * g + i][col] = __builtin_bit_cast(unsigned short, bl);
        }
      }
    }
    barrier_lds();
  }

  // ---- FC head: out[n] = h1(63)[n] . Wfc + bfc; h1(63) in S1[0]. ----
  if (tid < 64) {
    const int r = tid & 15;
    const int q = tid >> 4;
    float acc = 0.f;
#pragma unroll
    for (int k = 0; k < 16; ++k) {
      int kk = 16 * q + k;
      float hv = __uint_as_float(((u32)S1H[0][r][kk]) << 16) +
                 __uint_as_float(((u32)S1L[0][r][kk]) << 16);
      acc += hv * WFC[kk];
    }
    RED[tid] = acc;
  }
  barrier_lds();
  if (tid < 16) {
    float o = RED[tid] + RED[tid + 16] + RED[tid + 32] + RED[tid + 48] +
              bfc[0];
    out[n0 + tid] = o;
  }
}

extern "C" void kernel_launch(void* const* d_in, const int* in_sizes, int n_in,
                              void* d_out, int out_size, void* d_ws,
                              size_t ws_size, hipStream_t stream) {
  (void)in_sizes; (void)n_in; (void)d_ws; (void)ws_size; (void)out_size;
  const float* x    = (const float*)d_in[0];
  const float* Wih0 = (const float*)d_in[1];
  const float* Whh0 = (const float*)d_in[2];
  const float* bih0 = (const float*)d_in[3];
  const float* bhh0 = (const float*)d_in[4];
  const float* Wih1 = (const float*)d_in[5];
  const float* Whh1 = (const float*)d_in[6];
  const float* bih1 = (const float*)d_in[7];
  const float* bhh1 = (const float*)d_in[8];
  const float* Wfc  = (const float*)d_in[9];
  const float* bfc  = (const float*)d_in[10];

  rnn2_fused_kernel<<<256, 512, 0, stream>>>(
      x, Wih0, Whh0, bih0, bhh0, Wih1, Whh1, bih1, bhh1, Wfc, bfc,
      (float*)d_out);
}